// Round 2
// baseline (1726.470 us; speedup 1.0000x reference)
//
#include <hip/hip_runtime.h>
#include <cfloat>

#define TT 16
#define KK 512
#define DD 128
#define BC 256       // b-rows per argmin block
#define N0 16777216  // 8192*16*128 (z_q_st)
#define N1 131072    // 8192*16     (tokens)

// numpy pairwise-sum (n<=128: 8 strided accumulators + tree combine) of x^2,
// reading 32 float4 from memory (global or LDS). Bit-exact vs np.sum(x*x,-1).
__device__ __forceinline__ float np_sum128_sq_f4(const float4* __restrict__ p) {
  float4 a = p[0], b = p[1];
  float r[8];
  r[0] = __fmul_rn(a.x, a.x); r[1] = __fmul_rn(a.y, a.y);
  r[2] = __fmul_rn(a.z, a.z); r[3] = __fmul_rn(a.w, a.w);
  r[4] = __fmul_rn(b.x, b.x); r[5] = __fmul_rn(b.y, b.y);
  r[6] = __fmul_rn(b.z, b.z); r[7] = __fmul_rn(b.w, b.w);
#pragma unroll
  for (int i = 1; i < 16; ++i) {
    a = p[2 * i]; b = p[2 * i + 1];
    r[0] = __fadd_rn(r[0], __fmul_rn(a.x, a.x));
    r[1] = __fadd_rn(r[1], __fmul_rn(a.y, a.y));
    r[2] = __fadd_rn(r[2], __fmul_rn(a.z, a.z));
    r[3] = __fadd_rn(r[3], __fmul_rn(a.w, a.w));
    r[4] = __fadd_rn(r[4], __fmul_rn(b.x, b.x));
    r[5] = __fadd_rn(r[5], __fmul_rn(b.y, b.y));
    r[6] = __fadd_rn(r[6], __fmul_rn(b.z, b.z));
    r[7] = __fadd_rn(r[7], __fmul_rn(b.w, b.w));
  }
  return __fadd_rn(__fadd_rn(__fadd_rn(r[0], r[1]), __fadd_rn(r[2], r[3])),
                   __fadd_rn(__fadd_rn(r[4], r[5]), __fadd_rn(r[6], r[7])));
}

// same pairwise order, but over an in-register float4[32]
__device__ __forceinline__ float np_sum128_sq_reg(const float4* c4) {
  float r[8];
  r[0] = __fmul_rn(c4[0].x, c4[0].x); r[1] = __fmul_rn(c4[0].y, c4[0].y);
  r[2] = __fmul_rn(c4[0].z, c4[0].z); r[3] = __fmul_rn(c4[0].w, c4[0].w);
  r[4] = __fmul_rn(c4[1].x, c4[1].x); r[5] = __fmul_rn(c4[1].y, c4[1].y);
  r[6] = __fmul_rn(c4[1].z, c4[1].z); r[7] = __fmul_rn(c4[1].w, c4[1].w);
#pragma unroll
  for (int i = 1; i < 16; ++i) {
    float4 a = c4[2 * i], b = c4[2 * i + 1];
    r[0] = __fadd_rn(r[0], __fmul_rn(a.x, a.x));
    r[1] = __fadd_rn(r[1], __fmul_rn(a.y, a.y));
    r[2] = __fadd_rn(r[2], __fmul_rn(a.z, a.z));
    r[3] = __fadd_rn(r[3], __fmul_rn(a.w, a.w));
    r[4] = __fadd_rn(r[4], __fmul_rn(b.x, b.x));
    r[5] = __fadd_rn(r[5], __fmul_rn(b.y, b.y));
    r[6] = __fadd_rn(r[6], __fmul_rn(b.z, b.z));
    r[7] = __fadd_rn(r[7], __fmul_rn(b.w, b.w));
  }
  return __fadd_rn(__fadd_rn(__fadd_rn(r[0], r[1]), __fadd_rn(r[2], r[3])),
                   __fadd_rn(__fadd_rn(r[4], r[5]), __fadd_rn(r[6], r[7])));
}

// Argmin kernel: lane holds codebook row k=k0+lane in 128 VGPRs; z row is
// wave-uniform (scalar-path loads). 4 waves x 2 passes cover all 512 k.
__global__ __launch_bounds__(256, 3) void vq_argmin(
    const float* __restrict__ z_e, const float* __restrict__ cb,
    float* __restrict__ out, int* __restrict__ used) {
  __shared__ float A_s[BC];
  __shared__ unsigned long long best_s[8][BC];  // 16 KB

  const int tid  = threadIdx.x;
  const int lane = tid & 63;
  const int w    = tid >> 6;
  const int t    = blockIdx.y;
  const int b0   = blockIdx.x * BC;

  // ---- prologue: ||z||^2 for this block's b-rows (np pairwise order) ----
  A_s[tid] = np_sum128_sq_f4(
      (const float4*)(z_e + ((size_t)(b0 + tid) * TT + t) * DD));
  __syncthreads();

#pragma unroll
  for (int pass = 0; pass < 2; ++pass) {
    const int kslot = pass * 4 + w;
    const int k0 = kslot * 64;
    const int k = k0 + lane;

    // lane-resident codebook row (128 VGPRs)
    float4 c4[32];
    const float4* cp = (const float4*)(cb + ((size_t)t * KK + k) * DD);
#pragma unroll
    for (int i = 0; i < 32; ++i) c4[i] = cp[i];
    const float q = np_sum128_sq_reg(c4);

    for (int b = 0; b < BC; ++b) {
      // wave-uniform z row -> scalar loads
      const float4* zp =
          (const float4*)(z_e + ((size_t)(b0 + b) * TT + t) * DD);
      float p = 0.0f;
#pragma unroll
      for (int d4 = 0; d4 < 32; ++d4) {
        float4 zz = zp[d4];
        p = __builtin_fmaf(zz.x, c4[d4].x, p);
        p = __builtin_fmaf(zz.y, c4[d4].y, p);
        p = __builtin_fmaf(zz.z, c4[d4].z, p);
        p = __builtin_fmaf(zz.w, c4[d4].w, p);
      }
      const float Ab = A_s[b];
      const float dist =
          __fadd_rn(__fsub_rn(Ab, __fmul_rn(2.0f, p)), q);

      // butterfly min across 64 lanes, then lowest tied lane (== lowest k)
      float mv = dist;
#pragma unroll
      for (int m = 32; m > 0; m >>= 1) mv = fminf(mv, __shfl_xor(mv, m, 64));
      unsigned long long mask = __ballot(dist == mv);
      int bl = __ffsll(mask) - 1;
      if (lane == 0)
        best_s[kslot][b] =
            ((unsigned long long)__float_as_uint(mv) << 32) |
            (unsigned)(k0 + bl);
    }
  }
  __syncthreads();

  // ---- merge 8 k-slots per b; write token; mark used ----
  {
    unsigned long long bb = best_s[0][tid];
#pragma unroll
    for (int s = 1; s < 8; ++s) {
      unsigned long long v = best_s[s][tid];
      bb = (v < bb) ? v : bb;
    }
    const int tok = (int)(bb & 0xffffffffULL);
    out[(size_t)N0 + (size_t)(b0 + tid) * TT + t] = (float)tok;
    atomicOr(&used[t * KK + tok], 1);
  }
}

// Epilogue: z_q_st = z + (c - z), loss partials. 8 rows per 256-thr block.
__global__ __launch_bounds__(256) void vq_epilogue(
    const float* __restrict__ z_e, const float* __restrict__ cb,
    float* __restrict__ out, float* __restrict__ loss_acc) {
  const int tid = threadIdx.x;
  const size_t r = (size_t)blockIdx.x * 8 + (tid >> 5);  // r = b*16 + t
  const int c32 = tid & 31;
  const int t = (int)(r & 15);

  const int tok = (int)out[(size_t)N0 + r];
  float4 cv = *(const float4*)(cb + ((size_t)t * KK + tok) * DD + c32 * 4);
  float4 zv = *(const float4*)(z_e + r * DD + c32 * 4);
  float4 o;
  o.x = __fadd_rn(zv.x, __fsub_rn(cv.x, zv.x));
  o.y = __fadd_rn(zv.y, __fsub_rn(cv.y, zv.y));
  o.z = __fadd_rn(zv.z, __fsub_rn(cv.z, zv.z));
  o.w = __fadd_rn(zv.w, __fsub_rn(cv.w, zv.w));
  *(float4*)(out + r * DD + c32 * 4) = o;

  float dx = zv.x - cv.x, dy = zv.y - cv.y, dz = zv.z - cv.z, dw = zv.w - cv.w;
  float lsum = dx * dx + dy * dy + dz * dz + dw * dw;
#pragma unroll
  for (int off = 32; off > 0; off >>= 1) lsum += __shfl_down(lsum, off, 64);
  if ((tid & 63) == 0) atomicAdd(loss_acc, lsum);
}

__global__ void vq_final(const float* __restrict__ loss_acc,
                         const int* __restrict__ used, float* __restrict__ out) {
  __shared__ int part[4];
  int tid = threadIdx.x;
  int c = 0;
  for (int i = tid; i < TT * KK; i += 256) c += used[i];
#pragma unroll
  for (int off = 32; off > 0; off >>= 1) c += __shfl_down(c, off, 64);
  if ((tid & 63) == 0) part[tid >> 6] = c;
  __syncthreads();
  if (tid == 0) {
    int tot = part[0] + part[1] + part[2] + part[3];
    out[(size_t)N0 + N1]     = 0.25f * loss_acc[0] / 16777216.0f;  // BETA*mean
    out[(size_t)N0 + N1 + 1] = (float)tot / 8192.0f;               // utilization
  }
}

extern "C" void kernel_launch(void* const* d_in, const int* in_sizes, int n_in,
                              void* d_out, int out_size, void* d_ws, size_t ws_size,
                              hipStream_t stream) {
  const float* z_e = (const float*)d_in[0];
  const float* cb  = (const float*)d_in[1];
  float* out = (float*)d_out;
  float* loss_acc = (float*)d_ws;
  int*   used     = (int*)((char*)d_ws + 64);
  hipMemsetAsync(d_ws, 0, 64 + TT * KK * sizeof(int), stream);
  vq_argmin<<<dim3(8192 / BC, TT), 256, 0, stream>>>(z_e, cb, out, used);
  vq_epilogue<<<N1 / 8, 256, 0, stream>>>(z_e, cb, out, loss_acc);
  vq_final<<<1, 256, 0, stream>>>(loss_acc, used, out);
}

// Round 3
// 365.786 us; speedup vs baseline: 4.7199x; 4.7199x over previous
//
#include <hip/hip_runtime.h>
#include <cfloat>

#define TT 16
#define KK 512
#define DD 128
#define BT 128        // b-rows per block
#define KTILE 128     // k-rows per chunk
#define DC 64         // d-chunk staged in LDS
#define SW 68         // LDS row stride (floats): mult of 4, ==4 mod 32
#define N0 16777216   // 8192*16*128 (z_q_st)
#define N1 131072     // 8192*16     (tokens)

// numpy pairwise-sum (n<=128: 8 strided accumulators + tree combine) of x^2
__device__ __forceinline__ float np_sum128_sq_f4(const float4* __restrict__ p) {
  float4 a = p[0], b = p[1];
  float r[8];
  r[0] = __fmul_rn(a.x, a.x); r[1] = __fmul_rn(a.y, a.y);
  r[2] = __fmul_rn(a.z, a.z); r[3] = __fmul_rn(a.w, a.w);
  r[4] = __fmul_rn(b.x, b.x); r[5] = __fmul_rn(b.y, b.y);
  r[6] = __fmul_rn(b.z, b.z); r[7] = __fmul_rn(b.w, b.w);
#pragma unroll
  for (int i = 1; i < 16; ++i) {
    a = p[2 * i]; b = p[2 * i + 1];
    r[0] = __fadd_rn(r[0], __fmul_rn(a.x, a.x));
    r[1] = __fadd_rn(r[1], __fmul_rn(a.y, a.y));
    r[2] = __fadd_rn(r[2], __fmul_rn(a.z, a.z));
    r[3] = __fadd_rn(r[3], __fmul_rn(a.w, a.w));
    r[4] = __fadd_rn(r[4], __fmul_rn(b.x, b.x));
    r[5] = __fadd_rn(r[5], __fmul_rn(b.y, b.y));
    r[6] = __fadd_rn(r[6], __fmul_rn(b.z, b.z));
    r[7] = __fadd_rn(r[7], __fmul_rn(b.w, b.w));
  }
  return __fadd_rn(__fadd_rn(__fadd_rn(r[0], r[1]), __fadd_rn(r[2], r[3])),
                   __fadd_rn(__fadd_rn(r[4], r[5]), __fadd_rn(r[6], r[7])));
}

__global__ __launch_bounds__(256, 2) void vq_main(
    const float* __restrict__ z_e, const float* __restrict__ cb,
    float* __restrict__ out, float* __restrict__ loss_part,
    int* __restrict__ used) {
  __shared__ alignas(16) float z_s[BT * SW];     // 34.8 KB (reused for merge)
  __shared__ alignas(16) float c_s[KTILE * SW];  // 34.8 KB
  __shared__ float A_s[BT];
  __shared__ float q_s[KTILE];
  __shared__ int   tok_s[BT];
  __shared__ float wred[4];

  const int tid = threadIdx.x;
  const int t   = blockIdx.y;
  const int b0  = blockIdx.x * BT;
  const int bt  = tid & 15;         // b sub-index: rows bt + 16*i
  const int kt  = tid >> 4;         // k sub-index: cols kt + 16*j

  // ||z||^2 for this block's rows (np pairwise order), from global (L2/L3)
  if (tid < BT)
    A_s[tid] = np_sum128_sq_f4(
        (const float4*)(z_e + ((size_t)(b0 + tid) * TT + t) * DD));

  float bestv[8];
  int   bestk[8];
#pragma unroll
  for (int i = 0; i < 8; ++i) { bestv[i] = FLT_MAX; bestk[i] = 0; }

#pragma unroll 1
  for (int kc = 0; kc < KK / KTILE; ++kc) {
    __syncthreads();  // prior kchunk done reading q_s
    if (tid < KTILE)
      q_s[tid] = np_sum128_sq_f4(
          (const float4*)(cb + ((size_t)t * KK + kc * KTILE + tid) * DD));

    float acc[8][8];
#pragma unroll
    for (int i = 0; i < 8; ++i)
#pragma unroll
      for (int j = 0; j < 8; ++j) acc[i][j] = 0.0f;

#pragma unroll 1
    for (int dc = 0; dc < DD / DC; ++dc) {
      __syncthreads();  // prior compute done reading z_s/c_s
      // stage z chunk: 128 rows x 16 float4
#pragma unroll
      for (int it = 0; it < 8; ++it) {
        int idx = tid + it * 256;
        int r = idx >> 4, cc = idx & 15;
        float4 v = *(const float4*)(z_e + ((size_t)(b0 + r) * TT + t) * DD +
                                    dc * DC + cc * 4);
        *(float4*)(z_s + r * SW + cc * 4) = v;
      }
      // stage c chunk: 128 rows x 16 float4
#pragma unroll
      for (int it = 0; it < 8; ++it) {
        int idx = tid + it * 256;
        int r = idx >> 4, cc = idx & 15;
        float4 v = *(const float4*)(cb + ((size_t)t * KK + kc * KTILE + r) * DD +
                                    dc * DC + cc * 4);
        *(float4*)(c_s + r * SW + cc * 4) = v;
      }
      __syncthreads();

#pragma unroll 2
      for (int d4 = 0; d4 < DC / 4; ++d4) {
        float4 a[8], c[8];
#pragma unroll
        for (int i = 0; i < 8; ++i)
          a[i] = *(const float4*)(z_s + (bt + 16 * i) * SW + d4 * 4);
#pragma unroll
        for (int j = 0; j < 8; ++j)
          c[j] = *(const float4*)(c_s + (kt + 16 * j) * SW + d4 * 4);
#pragma unroll
        for (int i = 0; i < 8; ++i)
#pragma unroll
          for (int j = 0; j < 8; ++j) {
            float s = acc[i][j];
            s = __builtin_fmaf(a[i].x, c[j].x, s);
            s = __builtin_fmaf(a[i].y, c[j].y, s);
            s = __builtin_fmaf(a[i].z, c[j].z, s);
            s = __builtin_fmaf(a[i].w, c[j].w, s);
            acc[i][j] = s;
          }
      }
    }

    // distances, reference rounding; per-thread k order is increasing
#pragma unroll
    for (int i = 0; i < 8; ++i) {
      float Ai = A_s[bt + 16 * i];
#pragma unroll
      for (int j = 0; j < 8; ++j) {
        float dist =
            __fadd_rn(__fsub_rn(Ai, __fmul_rn(2.0f, acc[i][j])), q_s[kt + 16 * j]);
        if (dist < bestv[i]) { bestv[i] = dist; bestk[i] = kc * KTILE + kt + 16 * j; }
      }
    }
  }

  // ---- cross-thread argmin merge (reuse z_s as u64[BT][16]) ----
  __syncthreads();
  unsigned long long* best_s = (unsigned long long*)z_s;
#pragma unroll
  for (int i = 0; i < 8; ++i)
    best_s[(bt + 16 * i) * 16 + kt] =
        ((unsigned long long)__float_as_uint(bestv[i]) << 32) | (unsigned)bestk[i];
  __syncthreads();
  if (tid < BT) {
    unsigned long long bb = best_s[tid * 16];
#pragma unroll
    for (int g = 1; g < 16; ++g) {
      unsigned long long v = best_s[tid * 16 + g];
      bb = (v < bb) ? v : bb;
    }
    const int tok = (int)(bb & 0xffffffffULL);
    tok_s[tid] = tok;
    out[(size_t)N0 + (size_t)(b0 + tid) * TT + t] = (float)tok;
    atomicOr(&used[t * KK + tok], 1);
  }
  __syncthreads();

  // ---- epilogue: z_q_st = z + (c - z), loss partial (block-local) ----
  float lsum = 0.0f;
#pragma unroll
  for (int it = 0; it < 16; ++it) {
    int idx = tid + it * 256;
    int r = idx >> 5, c = idx & 31;
    int k = tok_s[r];
    float4 cv = *(const float4*)(cb + ((size_t)t * KK + k) * DD + c * 4);
    float4 zv = *(const float4*)(z_e + ((size_t)(b0 + r) * TT + t) * DD + c * 4);
    float4 o;
    o.x = __fadd_rn(zv.x, __fsub_rn(cv.x, zv.x));
    o.y = __fadd_rn(zv.y, __fsub_rn(cv.y, zv.y));
    o.z = __fadd_rn(zv.z, __fsub_rn(cv.z, zv.z));
    o.w = __fadd_rn(zv.w, __fsub_rn(cv.w, zv.w));
    *(float4*)(out + ((size_t)(b0 + r) * TT + t) * DD + c * 4) = o;
    float dx = zv.x - cv.x, dy = zv.y - cv.y, dz = zv.z - cv.z, dw = zv.w - cv.w;
    lsum += dx * dx + dy * dy + dz * dz + dw * dw;
  }
#pragma unroll
  for (int off = 32; off > 0; off >>= 1) lsum += __shfl_down(lsum, off, 64);
  if ((tid & 63) == 0) wred[tid >> 6] = lsum;
  __syncthreads();
  if (tid == 0)
    loss_part[blockIdx.y * 64 + blockIdx.x] =
        wred[0] + wred[1] + wred[2] + wred[3];
}

__global__ void vq_final(const float* __restrict__ loss_part,
                         const int* __restrict__ used, float* __restrict__ out) {
  __shared__ float partf[4];
  __shared__ int   parti[4];
  int tid = threadIdx.x;
  float ls = 0.0f;
  for (int i = tid; i < 1024; i += 256) ls += loss_part[i];
  int c = 0;
  for (int i = tid; i < TT * KK; i += 256) c += used[i];
#pragma unroll
  for (int off = 32; off > 0; off >>= 1) {
    ls += __shfl_down(ls, off, 64);
    c  += __shfl_down(c, off, 64);
  }
  if ((tid & 63) == 0) { partf[tid >> 6] = ls; parti[tid >> 6] = c; }
  __syncthreads();
  if (tid == 0) {
    float lt = partf[0] + partf[1] + partf[2] + partf[3];
    int   tot = parti[0] + parti[1] + parti[2] + parti[3];
    out[(size_t)N0 + N1]     = 0.25f * lt / 16777216.0f;  // BETA * mean
    out[(size_t)N0 + N1 + 1] = (float)tot / 8192.0f;      // utilization
  }
}

extern "C" void kernel_launch(void* const* d_in, const int* in_sizes, int n_in,
                              void* d_out, int out_size, void* d_ws, size_t ws_size,
                              hipStream_t stream) {
  const float* z_e = (const float*)d_in[0];
  const float* cb  = (const float*)d_in[1];
  float* out = (float*)d_out;
  float* loss_part = (float*)d_ws;                     // 1024 floats
  int*   used      = (int*)((char*)d_ws + 4096);       // 8192 ints
  hipMemsetAsync(d_ws, 0, 4096 + TT * KK * sizeof(int), stream);
  vq_main<<<dim3(8192 / BT, TT), 256, 0, stream>>>(z_e, cb, out, loss_part, used);
  vq_final<<<1, 256, 0, stream>>>(loss_part, used, out);
}